// Round 1
// baseline (1349.962 us; speedup 1.0000x reference)
//
#include <hip/hip_runtime.h>
#include <cstddef>

#define HW   512
#define NPIX (HW*HW)
#define NP   (NPIX + 64)     // plane stride (floats), padded
#define NC   21

__device__ __forceinline__ float fexp2(float x) { return __builtin_amdgcn_exp2f(x); }

#define KB_EXP (-0.08014972449f)          /* -0.5/9 * log2(e) */
#define LOG2E  (1.4426950408889634f)

#define KSP_INIT {0.13533528f, 0.24935221f, 0.41111229f, 0.60653066f, 0.80073740f, \
                  0.94595947f, 1.00000000f, 0.94595947f, 0.80073740f, 0.60653066f, \
                  0.41111229f, 0.24935221f, 0.13533528f}

// ---------- setup: transpose unaries/rgb into channel-planar layout ----------
__global__ void k_setup(const float* __restrict__ unaries, const float* __restrict__ rgb,
                        float* __restrict__ u, float* __restrict__ q, float* __restrict__ rgbT) {
    int p = blockIdx.x * 256 + threadIdx.x;       // p = a*512 + b  (a = W-index, b = H-index)
    int a = p >> 9, b = p & 511;
    int src = b * 512 + a;
    #pragma unroll
    for (int c = 0; c < NC; ++c) {
        float v = unaries[src * NC + c];
        u[c * NP + p] = v;
        q[c * NP + p] = v;
    }
    #pragma unroll
    for (int ch = 0; ch < 3; ++ch) rgbT[ch * NP + p] = rgb[src * 3 + ch];
}

// ---------- prep: invS table + fused matrices M1=-Cm@Wsp, M2=-Cm@Wbl ----------
__global__ void k_prep(const float* __restrict__ Wsp, const float* __restrict__ Wbl,
                       const float* __restrict__ Cm,
                       float* __restrict__ invS, float* __restrict__ M1, float* __restrict__ M2) {
    int t = threadIdx.x;   // 512 threads, 1 block
    const float KSP[13] = KSP_INIT;
    {
        float s = 0.f;
        #pragma unroll
        for (int d = 0; d < 13; ++d) {
            int i = t + d - 6;
            if ((unsigned)i < 512u) s += KSP[d];
        }
        invS[t] = 1.0f / s;
    }
    if (t < NC * NC) {
        int c = t / NC, j = t % NC;
        float s1 = 0.f, s2 = 0.f;
        for (int k = 0; k < NC; ++k) {
            float cm = Cm[c * NC + k];
            s1 += cm * Wsp[k * NC + j];
            s2 += cm * Wbl[k * NC + j];
        }
        M1[t] = -s1;
        M2[t] = -s2;
    }
}

// ---------- bilateral norm (channel independent): store reciprocal ----------
__global__ void k_blnorm(const float* __restrict__ rgbT, float* __restrict__ inorm) {
    int a  = blockIdx.x;
    int b0 = threadIdx.x << 2;      // 128 threads * 4 px = 512
    float cr[3][4];
    #pragma unroll
    for (int ch = 0; ch < 3; ++ch) {
        float4 f = *reinterpret_cast<const float4*>(rgbT + ch * NP + a * HW + b0);
        cr[ch][0] = f.x; cr[ch][1] = f.y; cr[ch][2] = f.z; cr[ch][3] = f.w;
    }
    float sum[4] = {0.f, 0.f, 0.f, 0.f};
    #pragma unroll 1
    for (int dy = -6; dy <= 6; ++dy) {
        int ar = a + dy;
        if ((unsigned)ar >= 512u) continue;
        int rowoff = ar * HW + b0 - 8;
        float nr[3][20];
        #pragma unroll
        for (int ch = 0; ch < 3; ++ch)
            #pragma unroll
            for (int tq = 0; tq < 5; ++tq) {
                float4 f = *reinterpret_cast<const float4*>(rgbT + ch * NP + rowoff + 4 * tq);
                nr[ch][4*tq+0] = f.x; nr[ch][4*tq+1] = f.y; nr[ch][4*tq+2] = f.z; nr[ch][4*tq+3] = f.w;
            }
        float spk = KB_EXP * (float)(dy * dy);
        #pragma unroll
        for (int j = 0; j < 4; ++j) {
            #pragma unroll
            for (int dx = 0; dx < 13; ++dx) {
                int ic = j + dx + 2;
                float d0 = cr[0][j] - nr[0][ic];
                float d1 = cr[1][j] - nr[1][ic];
                float d2 = cr[2][j] - nr[2][ic];
                float dcol = d0*d0 + d1*d1 + d2*d2;
                float arg = KB_EXP * dcol + (spk + KB_EXP * (float)((dx-6)*(dx-6)));
                bool ok = (unsigned)(b0 + j + dx - 6) < 512u;
                sum[j] += ok ? fexp2(arg) : 0.f;
            }
        }
    }
    float4 r;
    r.x = 1.0f / sum[0]; r.y = 1.0f / sum[1]; r.z = 1.0f / sum[2]; r.w = 1.0f / sum[3];
    *reinterpret_cast<float4*>(inorm + a * HW + b0) = r;
}

// ---------- softmax over channels ----------
__global__ void k_softmax(const float* __restrict__ q, float* __restrict__ p) {
    int i = blockIdx.x * 256 + threadIdx.x;
    float v[NC];
    float m = -1e30f;
    #pragma unroll
    for (int c = 0; c < NC; ++c) { v[c] = q[c * NP + i]; m = fmaxf(m, v[c]); }
    float s = 0.f;
    #pragma unroll
    for (int c = 0; c < NC; ++c) { v[c] = fexp2((v[c] - m) * LOG2E); s += v[c]; }
    float r = 1.0f / s;
    #pragma unroll
    for (int c = 0; c < NC; ++c) p[c * NP + i] = v[c] * r;
}

// ---------- spatial pass along b (contiguous axis) ----------
__global__ void k_spatial_h(const float* __restrict__ src, float* __restrict__ dst) {
    int idx = blockIdx.x * 256 + threadIdx.x;          // 21*512*128 threads
    int b0 = (idx & 127) << 2;
    int a  = (idx >> 7) & 511;
    int c  = idx >> 16;
    const float* row = src + c * NP + a * HW;
    float pv[20];
    #pragma unroll
    for (int tq = 0; tq < 5; ++tq) {
        float4 f = *reinterpret_cast<const float4*>(row + b0 - 8 + 4 * tq);
        pv[4*tq+0] = f.x; pv[4*tq+1] = f.y; pv[4*tq+2] = f.z; pv[4*tq+3] = f.w;
    }
    const float KSP[13] = KSP_INIT;
    float out[4] = {0.f, 0.f, 0.f, 0.f};
    if (b0 >= 8 && b0 <= 500) {
        #pragma unroll
        for (int d = 0; d < 13; ++d)
            #pragma unroll
            for (int j = 0; j < 4; ++j) out[j] += KSP[d] * pv[j + d + 2];
    } else {
        #pragma unroll
        for (int d = 0; d < 13; ++d)
            #pragma unroll
            for (int j = 0; j < 4; ++j) {
                bool ok = (unsigned)(b0 + j + d - 6) < 512u;
                out[j] += (ok ? KSP[d] : 0.f) * pv[j + d + 2];
            }
    }
    float4 r; r.x = out[0]; r.y = out[1]; r.z = out[2]; r.w = out[3];
    *reinterpret_cast<float4*>(dst + c * NP + a * HW + b0) = r;
}

// ---------- spatial pass along a (strided axis) + normalization ----------
__global__ void k_spatial_v(const float* __restrict__ src, float* __restrict__ dst,
                            const float* __restrict__ invS) {
    int idx = blockIdx.x * 256 + threadIdx.x;
    int b0 = (idx & 127) << 2;
    int a  = (idx >> 7) & 511;
    int c  = idx >> 16;
    const float* col = src + c * NP + b0;
    const float KSP[13] = KSP_INIT;
    float out[4] = {0.f, 0.f, 0.f, 0.f};
    #pragma unroll
    for (int d = 0; d < 13; ++d) {
        int ar = a + d - 6;
        if ((unsigned)ar < 512u) {
            float4 f = *reinterpret_cast<const float4*>(col + ar * HW);
            out[0] += KSP[d] * f.x; out[1] += KSP[d] * f.y;
            out[2] += KSP[d] * f.z; out[3] += KSP[d] * f.w;
        }
    }
    float isa = invS[a];
    float4 iv = *reinterpret_cast<const float4*>(invS + b0);
    float4 r;
    r.x = out[0] * isa * iv.x; r.y = out[1] * isa * iv.y;
    r.z = out[2] * isa * iv.z; r.w = out[3] * isa * iv.w;
    *reinterpret_cast<float4*>(dst + c * NP + a * HW + b0) = r;
}

// ---------- bilateral filter: 4 px/thread, 7-channel chunk per block ----------
__global__ void k_bilateral(const float* __restrict__ p, const float* __restrict__ rgbT,
                            const float* __restrict__ inorm, float* __restrict__ bl) {
    int a     = blockIdx.x;
    int cbase = blockIdx.y * 7;
    int b0    = threadIdx.x << 2;        // 128 threads
    float cr[3][4];
    #pragma unroll
    for (int ch = 0; ch < 3; ++ch) {
        float4 f = *reinterpret_cast<const float4*>(rgbT + ch * NP + a * HW + b0);
        cr[ch][0] = f.x; cr[ch][1] = f.y; cr[ch][2] = f.z; cr[ch][3] = f.w;
    }
    float acc[7][4];
    #pragma unroll
    for (int ci = 0; ci < 7; ++ci)
        #pragma unroll
        for (int j = 0; j < 4; ++j) acc[ci][j] = 0.f;

    #pragma unroll 1
    for (int dy = -6; dy <= 6; ++dy) {
        int ar = a + dy;
        if ((unsigned)ar >= 512u) continue;
        int rowoff = ar * HW + b0 - 8;
        // neighbor rgb window [b0-8, b0+11]
        float nr[3][20];
        #pragma unroll
        for (int ch = 0; ch < 3; ++ch)
            #pragma unroll
            for (int tq = 0; tq < 5; ++tq) {
                float4 f = *reinterpret_cast<const float4*>(rgbT + ch * NP + rowoff + 4 * tq);
                nr[ch][4*tq+0] = f.x; nr[ch][4*tq+1] = f.y; nr[ch][4*tq+2] = f.z; nr[ch][4*tq+3] = f.w;
            }
        float spk = KB_EXP * (float)(dy * dy);
        float w[4][13];
        #pragma unroll
        for (int j = 0; j < 4; ++j) {
            #pragma unroll
            for (int dx = 0; dx < 13; ++dx) {
                int ic = j + dx + 2;
                float d0 = cr[0][j] - nr[0][ic];
                float d1 = cr[1][j] - nr[1][ic];
                float d2 = cr[2][j] - nr[2][ic];
                float dcol = d0*d0 + d1*d1 + d2*d2;
                float arg = KB_EXP * dcol + (spk + KB_EXP * (float)((dx-6)*(dx-6)));
                bool ok = (unsigned)(b0 + j + dx - 6) < 512u;
                w[j][dx] = ok ? fexp2(arg) : 0.f;
            }
        }
        #pragma unroll
        for (int ci = 0; ci < 7; ++ci) {
            const float* prow = p + (cbase + ci) * NP + rowoff;
            float pv[20];
            #pragma unroll
            for (int tq = 0; tq < 5; ++tq) {
                float4 f = *reinterpret_cast<const float4*>(prow + 4 * tq);
                pv[4*tq+0] = f.x; pv[4*tq+1] = f.y; pv[4*tq+2] = f.z; pv[4*tq+3] = f.w;
            }
            #pragma unroll
            for (int j = 0; j < 4; ++j)
                #pragma unroll
                for (int dx = 0; dx < 13; ++dx)
                    acc[ci][j] += w[j][dx] * pv[j + dx + 2];
        }
    }
    float4 rn = *reinterpret_cast<const float4*>(inorm + a * HW + b0);
    #pragma unroll
    for (int ci = 0; ci < 7; ++ci) {
        float4 r;
        r.x = acc[ci][0] * rn.x; r.y = acc[ci][1] * rn.y;
        r.z = acc[ci][2] * rn.z; r.w = acc[ci][3] * rn.w;
        *reinterpret_cast<float4*>(bl + (cbase + ci) * NP + a * HW + b0) = r;
    }
}

// ---------- combine: q = u + M1@sp + M2@bl ----------
__global__ void k_combine(const float* __restrict__ u, const float* __restrict__ sp,
                          const float* __restrict__ bl, const float* __restrict__ M1,
                          const float* __restrict__ M2, float* __restrict__ q) {
    __shared__ float m1[NC * NC], m2[NC * NC];
    int t = threadIdx.x;
    for (int i = t; i < NC * NC; i += 256) { m1[i] = M1[i]; m2[i] = M2[i]; }
    __syncthreads();
    int p4 = (blockIdx.x * 256 + t) << 2;
    float msg[NC][4];
    #pragma unroll
    for (int c = 0; c < NC; ++c)
        #pragma unroll
        for (int j = 0; j < 4; ++j) msg[c][j] = 0.f;
    #pragma unroll 3
    for (int k = 0; k < NC; ++k) {
        float4 s = *reinterpret_cast<const float4*>(sp + k * NP + p4);
        float4 b = *reinterpret_cast<const float4*>(bl + k * NP + p4);
        #pragma unroll
        for (int c = 0; c < NC; ++c) {
            float a1 = m1[c * NC + k], a2 = m2[c * NC + k];
            msg[c][0] += a1 * s.x + a2 * b.x;
            msg[c][1] += a1 * s.y + a2 * b.y;
            msg[c][2] += a1 * s.z + a2 * b.z;
            msg[c][3] += a1 * s.w + a2 * b.w;
        }
    }
    #pragma unroll
    for (int c = 0; c < NC; ++c) {
        float4 uu = *reinterpret_cast<const float4*>(u + c * NP + p4);
        float4 r;
        r.x = uu.x + msg[c][0]; r.y = uu.y + msg[c][1];
        r.z = uu.z + msg[c][2]; r.w = uu.w + msg[c][3];
        *reinterpret_cast<float4*>(q + c * NP + p4) = r;
    }
}

// ---------- final: planar q -> interleaved output ----------
__global__ void k_output(const float* __restrict__ q, float* __restrict__ out) {
    __shared__ float tile[256 * NC];
    int t = threadIdx.x;
    int p0 = blockIdx.x * 256;
    #pragma unroll
    for (int c = 0; c < NC; ++c) tile[t * NC + c] = q[c * NP + p0 + t];
    __syncthreads();
    for (int i = t; i < 256 * NC; i += 256) out[(size_t)p0 * NC + i] = tile[i];
}

extern "C" void kernel_launch(void* const* d_in, const int* in_sizes, int n_in,
                              void* d_out, int out_size, void* d_ws, size_t ws_size,
                              hipStream_t stream) {
    const float* unaries = (const float*)d_in[0];
    const float* rgb     = (const float*)d_in[1];
    const float* Wsp     = (const float*)d_in[2];
    const float* Wbl     = (const float*)d_in[3];
    const float* Cm      = (const float*)d_in[4];
    float* out = (float*)d_out;
    float* ws  = (float*)d_ws;

    size_t needed = ((size_t)109 * NP + 2048) * sizeof(float);
    if (ws_size < needed) return;   // cannot run; bench will report mismatch

    float* u     = ws;
    float* q     = ws + (size_t)21 * NP;
    float* p     = ws + (size_t)42 * NP;
    float* A     = ws + (size_t)63 * NP;   // tmp for spatial pass1, then bilateral result
    float* B     = ws + (size_t)84 * NP;   // spatial result
    float* rgbT  = ws + (size_t)105 * NP;  // 3 planes
    float* inorm = ws + (size_t)108 * NP;  // 1 plane
    float* invS  = ws + (size_t)109 * NP;  // 512
    float* M1    = invS + 512;             // 441
    float* M2    = M1 + 441;               // 441

    k_setup<<<NPIX / 256, 256, 0, stream>>>(unaries, rgb, u, q, rgbT);
    k_prep<<<1, 512, 0, stream>>>(Wsp, Wbl, Cm, invS, M1, M2);
    k_blnorm<<<HW, 128, 0, stream>>>(rgbT, inorm);

    for (int it = 0; it < 5; ++it) {
        k_softmax<<<NPIX / 256, 256, 0, stream>>>(q, p);
        k_spatial_h<<<(NC * 512 * 128) / 256, 256, 0, stream>>>(p, A);
        k_spatial_v<<<(NC * 512 * 128) / 256, 256, 0, stream>>>(A, B, invS);
        k_bilateral<<<dim3(HW, 3), 128, 0, stream>>>(p, rgbT, inorm, A);
        k_combine<<<(NPIX / 4) / 256, 256, 0, stream>>>(u, B, A, M1, M2, q);
    }
    k_output<<<NPIX / 256, 256, 0, stream>>>(q, out);
}

// Round 2
// 1105.410 us; speedup vs baseline: 1.2212x; 1.2212x over previous
//
#include <hip/hip_runtime.h>
#include <cstddef>

#define HW   512
#define NPIX (HW*HW)
#define NP   (NPIX + 64)     // plane stride (floats), padded
#define NC   21

__device__ __forceinline__ float fexp2(float x) { return __builtin_amdgcn_exp2f(x); }

#define KB_EXP (-0.08014972449f)          /* -0.5/9 * log2(e) */
#define LOG2E  (1.4426950408889634f)

#define KSP_INIT {0.13533528f, 0.24935221f, 0.41111229f, 0.60653066f, 0.80073740f, \
                  0.94595947f, 1.00000000f, 0.94595947f, 0.80073740f, 0.60653066f, \
                  0.41111229f, 0.24935221f, 0.13533528f}

// ---------- setup: transpose unaries/rgb into channel-planar layout ----------
__global__ void k_setup(const float* __restrict__ unaries, const float* __restrict__ rgb,
                        float* __restrict__ u, float* __restrict__ q, float* __restrict__ rgbT) {
    int p = blockIdx.x * 256 + threadIdx.x;       // p = a*512 + b
    int a = p >> 9, b = p & 511;
    int src = b * 512 + a;
    #pragma unroll
    for (int c = 0; c < NC; ++c) {
        float v = unaries[src * NC + c];
        u[c * NP + p] = v;
        q[c * NP + p] = v;
    }
    #pragma unroll
    for (int ch = 0; ch < 3; ++ch) rgbT[ch * NP + p] = rgb[src * 3 + ch];
}

// ---------- prep: invS table + fused matrices M1=-Cm@Wsp, M2=-Cm@Wbl ----------
__global__ void k_prep(const float* __restrict__ Wsp, const float* __restrict__ Wbl,
                       const float* __restrict__ Cm,
                       float* __restrict__ invS, float* __restrict__ M1, float* __restrict__ M2) {
    int t = threadIdx.x;   // 512 threads, 1 block
    const float KSP[13] = KSP_INIT;
    {
        float s = 0.f;
        #pragma unroll
        for (int d = 0; d < 13; ++d) {
            int i = t + d - 6;
            if ((unsigned)i < 512u) s += KSP[d];
        }
        invS[t] = 1.0f / s;
    }
    if (t < NC * NC) {
        int c = t / NC, j = t % NC;
        float s1 = 0.f, s2 = 0.f;
        for (int k = 0; k < NC; ++k) {
            float cm = Cm[c * NC + k];
            s1 += cm * Wsp[k * NC + j];
            s2 += cm * Wbl[k * NC + j];
        }
        M1[t] = -s1;
        M2[t] = -s2;
    }
}

// ---------- bilateral norm partial sums (dy halves) ----------
__global__ void k_blnorm_part(const float* __restrict__ rgbT,
                              float* __restrict__ n0, float* __restrict__ n1) {
    int bid = blockIdx.x;            // 1024 = 512 rows * 2 halves
    int z = bid >> 9, a = bid & 511;
    int b0 = threadIdx.x << 2;       // 128 threads * 4 px
    float cr[3][4];
    #pragma unroll
    for (int ch = 0; ch < 3; ++ch) {
        float4 f = *reinterpret_cast<const float4*>(rgbT + ch * NP + a * HW + b0);
        cr[ch][0] = f.x; cr[ch][1] = f.y; cr[ch][2] = f.z; cr[ch][3] = f.w;
    }
    float sum[4] = {0.f, 0.f, 0.f, 0.f};
    int dylo = z ? 1 : -6, dyhi = z ? 6 : 0;
    #pragma unroll 1
    for (int dy = dylo; dy <= dyhi; ++dy) {
        int ar = a + dy;
        if ((unsigned)ar >= 512u) continue;
        int rowoff = ar * HW + b0 - 8;
        float nr[3][20];
        #pragma unroll
        for (int ch = 0; ch < 3; ++ch)
            #pragma unroll
            for (int tq = 0; tq < 5; ++tq) {
                float4 f = *reinterpret_cast<const float4*>(rgbT + ch * NP + rowoff + 4 * tq);
                nr[ch][4*tq+0] = f.x; nr[ch][4*tq+1] = f.y; nr[ch][4*tq+2] = f.z; nr[ch][4*tq+3] = f.w;
            }
        float spk = KB_EXP * (float)(dy * dy);
        #pragma unroll
        for (int j = 0; j < 4; ++j) {
            #pragma unroll
            for (int dx = 0; dx < 13; ++dx) {
                int ic = j + dx + 2;
                float d0 = cr[0][j] - nr[0][ic];
                float d1 = cr[1][j] - nr[1][ic];
                float d2 = cr[2][j] - nr[2][ic];
                float dcol = d0*d0 + d1*d1 + d2*d2;
                float arg = KB_EXP * dcol + (spk + KB_EXP * (float)((dx-6)*(dx-6)));
                bool ok = (unsigned)(b0 + j + dx - 6) < 512u;
                sum[j] += ok ? fexp2(arg) : 0.f;
            }
        }
    }
    float4 r; r.x = sum[0]; r.y = sum[1]; r.z = sum[2]; r.w = sum[3];
    float* dst = z ? n1 : n0;
    *reinterpret_cast<float4*>(dst + a * HW + b0) = r;
}

__global__ void k_invnorm(const float* __restrict__ n0, const float* __restrict__ n1,
                          float* __restrict__ inorm) {
    int i = blockIdx.x * 256 + threadIdx.x;
    inorm[i] = 1.0f / (n0[i] + n1[i]);
}

// ---------- softmax over channels, 4 px/thread ----------
__global__ void k_softmax(const float* __restrict__ q, float* __restrict__ p) {
    int i4 = (blockIdx.x * 256 + threadIdx.x) << 2;
    float v[NC][4];
    float m[4] = {-1e30f, -1e30f, -1e30f, -1e30f};
    #pragma unroll
    for (int c = 0; c < NC; ++c) {
        float4 f = *reinterpret_cast<const float4*>(q + c * NP + i4);
        v[c][0] = f.x; v[c][1] = f.y; v[c][2] = f.z; v[c][3] = f.w;
        #pragma unroll
        for (int j = 0; j < 4; ++j) m[j] = fmaxf(m[j], v[c][j]);
    }
    float s[4] = {0.f, 0.f, 0.f, 0.f};
    #pragma unroll
    for (int c = 0; c < NC; ++c)
        #pragma unroll
        for (int j = 0; j < 4; ++j) { v[c][j] = fexp2((v[c][j] - m[j]) * LOG2E); s[j] += v[c][j]; }
    float r[4];
    #pragma unroll
    for (int j = 0; j < 4; ++j) r[j] = 1.0f / s[j];
    #pragma unroll
    for (int c = 0; c < NC; ++c) {
        float4 f;
        f.x = v[c][0] * r[0]; f.y = v[c][1] * r[1];
        f.z = v[c][2] * r[2]; f.w = v[c][3] * r[3];
        *reinterpret_cast<float4*>(p + c * NP + i4) = f;
    }
}

// ---------- spatial pass along b (contiguous axis) ----------
__global__ void k_spatial_h(const float* __restrict__ src, float* __restrict__ dst) {
    int idx = blockIdx.x * 256 + threadIdx.x;          // 21*512*128 threads
    int b0 = (idx & 127) << 2;
    int a  = (idx >> 7) & 511;
    int c  = idx >> 16;
    const float* row = src + c * NP + a * HW;
    float pv[20];
    #pragma unroll
    for (int tq = 0; tq < 5; ++tq) {
        float4 f = *reinterpret_cast<const float4*>(row + b0 - 8 + 4 * tq);
        pv[4*tq+0] = f.x; pv[4*tq+1] = f.y; pv[4*tq+2] = f.z; pv[4*tq+3] = f.w;
    }
    const float KSP[13] = KSP_INIT;
    float out[4] = {0.f, 0.f, 0.f, 0.f};
    if (b0 >= 8 && b0 <= 500) {
        #pragma unroll
        for (int d = 0; d < 13; ++d)
            #pragma unroll
            for (int j = 0; j < 4; ++j) out[j] += KSP[d] * pv[j + d + 2];
    } else {
        #pragma unroll
        for (int d = 0; d < 13; ++d)
            #pragma unroll
            for (int j = 0; j < 4; ++j) {
                bool ok = (unsigned)(b0 + j + d - 6) < 512u;
                out[j] += (ok ? KSP[d] : 0.f) * pv[j + d + 2];
            }
    }
    float4 r; r.x = out[0]; r.y = out[1]; r.z = out[2]; r.w = out[3];
    *reinterpret_cast<float4*>(dst + c * NP + a * HW + b0) = r;
}

// ---------- spatial pass along a (strided axis) + normalization ----------
__global__ void k_spatial_v(const float* __restrict__ src, float* __restrict__ dst,
                            const float* __restrict__ invS) {
    int idx = blockIdx.x * 256 + threadIdx.x;
    int b0 = (idx & 127) << 2;
    int a  = (idx >> 7) & 511;
    int c  = idx >> 16;
    const float* col = src + c * NP + b0;
    const float KSP[13] = KSP_INIT;
    float out[4] = {0.f, 0.f, 0.f, 0.f};
    #pragma unroll
    for (int d = 0; d < 13; ++d) {
        int ar = a + d - 6;
        if ((unsigned)ar < 512u) {
            float4 f = *reinterpret_cast<const float4*>(col + ar * HW);
            out[0] += KSP[d] * f.x; out[1] += KSP[d] * f.y;
            out[2] += KSP[d] * f.z; out[3] += KSP[d] * f.w;
        }
    }
    float isa = invS[a];
    float4 iv = *reinterpret_cast<const float4*>(invS + b0);
    float4 r;
    r.x = out[0] * isa * iv.x; r.y = out[1] * isa * iv.y;
    r.z = out[2] * isa * iv.z; r.w = out[3] * isa * iv.w;
    *reinterpret_cast<float4*>(dst + c * NP + a * HW + b0) = r;
}

// ---------- bilateral: dy-half partials, XCD-swizzled 1D grid ----------
// grid = 3072 blocks (512 rows x 3 chunks x 2 halves), 128 threads, 4 px/thread
__global__ void k_bilateral(const float* __restrict__ p, const float* __restrict__ rgbT,
                            float* __restrict__ P0, float* __restrict__ P1) {
    int bid = blockIdx.x;
    int swz = (bid & 7) * 384 + (bid >> 3);     // 3072/8 = 384, bijective
    int z   = swz >= 1536;
    int rem = swz - z * 1536;
    int y   = rem >> 9;
    int a   = rem & 511;
    int cbase = y * 7;
    int b0    = threadIdx.x << 2;
    float cr[3][4];
    #pragma unroll
    for (int ch = 0; ch < 3; ++ch) {
        float4 f = *reinterpret_cast<const float4*>(rgbT + ch * NP + a * HW + b0);
        cr[ch][0] = f.x; cr[ch][1] = f.y; cr[ch][2] = f.z; cr[ch][3] = f.w;
    }
    float acc[7][4];
    #pragma unroll
    for (int ci = 0; ci < 7; ++ci)
        #pragma unroll
        for (int j = 0; j < 4; ++j) acc[ci][j] = 0.f;

    int dylo = z ? 1 : -6, dyhi = z ? 6 : 0;
    #pragma unroll 1
    for (int dy = dylo; dy <= dyhi; ++dy) {
        int ar = a + dy;
        if ((unsigned)ar >= 512u) continue;
        int rowoff = ar * HW + b0 - 8;
        float nr[3][20];
        #pragma unroll
        for (int ch = 0; ch < 3; ++ch)
            #pragma unroll
            for (int tq = 0; tq < 5; ++tq) {
                float4 f = *reinterpret_cast<const float4*>(rgbT + ch * NP + rowoff + 4 * tq);
                nr[ch][4*tq+0] = f.x; nr[ch][4*tq+1] = f.y; nr[ch][4*tq+2] = f.z; nr[ch][4*tq+3] = f.w;
            }
        float spk = KB_EXP * (float)(dy * dy);
        float w[4][13];
        #pragma unroll
        for (int j = 0; j < 4; ++j) {
            #pragma unroll
            for (int dx = 0; dx < 13; ++dx) {
                int ic = j + dx + 2;
                float d0 = cr[0][j] - nr[0][ic];
                float d1 = cr[1][j] - nr[1][ic];
                float d2 = cr[2][j] - nr[2][ic];
                float dcol = d0*d0 + d1*d1 + d2*d2;
                float arg = KB_EXP * dcol + (spk + KB_EXP * (float)((dx-6)*(dx-6)));
                bool ok = (unsigned)(b0 + j + dx - 6) < 512u;
                w[j][dx] = ok ? fexp2(arg) : 0.f;
            }
        }
        #pragma unroll
        for (int ci = 0; ci < 7; ++ci) {
            const float* prow = p + (cbase + ci) * NP + rowoff;
            float pv[20];
            #pragma unroll
            for (int tq = 0; tq < 5; ++tq) {
                float4 f = *reinterpret_cast<const float4*>(prow + 4 * tq);
                pv[4*tq+0] = f.x; pv[4*tq+1] = f.y; pv[4*tq+2] = f.z; pv[4*tq+3] = f.w;
            }
            #pragma unroll
            for (int j = 0; j < 4; ++j)
                #pragma unroll
                for (int dx = 0; dx < 13; ++dx)
                    acc[ci][j] += w[j][dx] * pv[j + dx + 2];
        }
    }
    float* dst = z ? P1 : P0;
    #pragma unroll
    for (int ci = 0; ci < 7; ++ci) {
        float4 r;
        r.x = acc[ci][0]; r.y = acc[ci][1]; r.z = acc[ci][2]; r.w = acc[ci][3];
        *reinterpret_cast<float4*>(dst + (cbase + ci) * NP + a * HW + b0) = r;
    }
}

// ---------- combine: q = u + M1@sp + M2@((P0+P1)*inorm), 1 px/thread ----------
__global__ void k_combine(const float* __restrict__ u, const float* sp,
                          const float* __restrict__ P0, const float* __restrict__ P1,
                          const float* __restrict__ inorm,
                          const float* __restrict__ M1, const float* __restrict__ M2,
                          float* q) {
    __shared__ float m1[NC * NC], m2[NC * NC];
    int t = threadIdx.x;
    for (int i = t; i < NC * NC; i += 256) { m1[i] = M1[i]; m2[i] = M2[i]; }
    __syncthreads();
    int px = blockIdx.x * 256 + t;
    float rn = inorm[px];
    float msg[NC];
    #pragma unroll
    for (int c = 0; c < NC; ++c) msg[c] = 0.f;
    #pragma unroll 3
    for (int k = 0; k < NC; ++k) {
        float s = sp[k * NP + px];
        float b = (P0[k * NP + px] + P1[k * NP + px]) * rn;
        #pragma unroll
        for (int c = 0; c < NC; ++c) msg[c] += m1[c * NC + k] * s + m2[c * NC + k] * b;
    }
    #pragma unroll
    for (int c = 0; c < NC; ++c) q[c * NP + px] = u[c * NP + px] + msg[c];
}

// ---------- final: planar q -> interleaved output ----------
__global__ void k_output(const float* __restrict__ q, float* __restrict__ out) {
    __shared__ float tile[256 * NC];
    int t = threadIdx.x;
    int p0 = blockIdx.x * 256;
    #pragma unroll
    for (int c = 0; c < NC; ++c) tile[t * NC + c] = q[c * NP + p0 + t];
    __syncthreads();
    for (int i = t; i < 256 * NC; i += 256) out[(size_t)p0 * NC + i] = tile[i];
}

extern "C" void kernel_launch(void* const* d_in, const int* in_sizes, int n_in,
                              void* d_out, int out_size, void* d_ws, size_t ws_size,
                              hipStream_t stream) {
    const float* unaries = (const float*)d_in[0];
    const float* rgb     = (const float*)d_in[1];
    const float* Wsp     = (const float*)d_in[2];
    const float* Wbl     = (const float*)d_in[3];
    const float* Cm      = (const float*)d_in[4];
    float* out = (float*)d_out;
    float* ws  = (float*)d_ws;

    size_t needed = ((size_t)109 * NP + 2048) * sizeof(float);
    if (ws_size < needed) return;

    float* u     = ws;                     // 21 planes
    float* q     = ws + (size_t)21 * NP;   // 21 planes (also holds spatial result)
    float* p     = ws + (size_t)42 * NP;   // 21 planes
    float* A     = ws + (size_t)63 * NP;   // 21 planes: spatial_h tmp, then bilateral partial 0
    float* P1    = ws + (size_t)84 * NP;   // 21 planes: bilateral partial 1 (+blnorm partials)
    float* rgbT  = ws + (size_t)105 * NP;  // 3 planes
    float* inorm = ws + (size_t)108 * NP;  // 1 plane
    float* invS  = ws + (size_t)109 * NP;  // 512
    float* M1    = invS + 512;             // 441
    float* M2    = M1 + 441;               // 441

    float* n0 = P1;          // blnorm partial planes (dead before bilateral's first P1 write)
    float* n1 = P1 + NP;

    k_setup<<<NPIX / 256, 256, 0, stream>>>(unaries, rgb, u, q, rgbT);
    k_prep<<<1, 512, 0, stream>>>(Wsp, Wbl, Cm, invS, M1, M2);
    k_blnorm_part<<<1024, 128, 0, stream>>>(rgbT, n0, n1);
    k_invnorm<<<NPIX / 256, 256, 0, stream>>>(n0, n1, inorm);

    for (int it = 0; it < 5; ++it) {
        k_softmax<<<NPIX / 4 / 256, 256, 0, stream>>>(q, p);
        k_spatial_h<<<(NC * 512 * 128) / 256, 256, 0, stream>>>(p, A);
        k_spatial_v<<<(NC * 512 * 128) / 256, 256, 0, stream>>>(A, q, invS);
        k_bilateral<<<3072, 128, 0, stream>>>(p, rgbT, A, P1);
        k_combine<<<NPIX / 256, 256, 0, stream>>>(u, q, A, P1, inorm, M1, M2, q);
    }
    k_output<<<NPIX / 256, 256, 0, stream>>>(q, out);
}